// Round 2
// baseline (83.222 us; speedup 1.0000x reference)
//
#include <hip/hip_runtime.h>
#include <hip/hip_bf16.h>

#define NN 512
#define BK 64

// ---------------- Kernel 1: S = P*P^T, k-major LDS, b64 reads, 2x2 micro ------
// Also zero-inits the accumulator + completion counter consumed by kernel 2
// (safe: stream ordering guarantees K1 fully completes before K2 starts).
__global__ __launch_bounds__(256) void sap_gemm(const float* __restrict__ P,
                                                float* __restrict__ S,
                                                float* __restrict__ g_acc,
                                                unsigned int* __restrict__ g_cnt) {
    __shared__ float As[BK][34];   // k-major: As[k][i]; pad 34 -> 8B-aligned rows,
    __shared__ float Bs[BK][34];   // conflict-free b64 compute reads
    const int t  = threadIdx.x;
    const int tx = t & 15, ty = t >> 4;
    const int i0 = blockIdx.y * 32, j0 = blockIdx.x * 32;

    if (blockIdx.x == 0 && blockIdx.y == 0 && t == 0) { *g_acc = 0.f; *g_cnt = 0u; }

    const int lr = t >> 3;        // 0..31: tile row being staged
    const int lc = (t & 7) * 4;   // 0..28: k-offset of this thread's float4

    float acc00 = 0.f, acc01 = 0.f, acc10 = 0.f, acc11 = 0.f;

    for (int kt = 0; kt < NN; kt += BK) {
        float4 a0 = *(const float4*)&P[(i0 + lr) * NN + kt + lc];
        float4 a1 = *(const float4*)&P[(i0 + lr) * NN + kt + lc + 32];
        float4 b0 = *(const float4*)&P[(j0 + lr) * NN + kt + lc];
        float4 b1 = *(const float4*)&P[(j0 + lr) * NN + kt + lc + 32];
        __syncthreads();                      // prev chunk's reads done
        As[lc + 0][lr] = a0.x;  As[lc + 1][lr] = a0.y;
        As[lc + 2][lr] = a0.z;  As[lc + 3][lr] = a0.w;
        As[lc + 32][lr] = a1.x; As[lc + 33][lr] = a1.y;
        As[lc + 34][lr] = a1.z; As[lc + 35][lr] = a1.w;
        Bs[lc + 0][lr] = b0.x;  Bs[lc + 1][lr] = b0.y;
        Bs[lc + 2][lr] = b0.z;  Bs[lc + 3][lr] = b0.w;
        Bs[lc + 32][lr] = b1.x; Bs[lc + 33][lr] = b1.y;
        Bs[lc + 34][lr] = b1.z; Bs[lc + 35][lr] = b1.w;
        __syncthreads();                      // staging visible
#pragma unroll
        for (int kk = 0; kk < BK; kk++) {
            float2 av = *(const float2*)&As[kk][2 * ty];
            float2 bv = *(const float2*)&Bs[kk][2 * tx];
            acc00 += av.x * bv.x; acc01 += av.x * bv.y;
            acc10 += av.y * bv.x; acc11 += av.y * bv.y;
        }
    }
    const int i = i0 + 2 * ty, j = j0 + 2 * tx;
    S[i * NN + j]           = acc00;
    S[i * NN + j + 1]       = acc01;
    S[(i + 1) * NN + j]     = acc10;
    S[(i + 1) * NN + j + 1] = acc11;
}

// ---------------- Kernel 2: per-anchor SmoothAP row + fused global reduce -----
__global__ __launch_bounds__(256) void sap_rows(const float* __restrict__ S,
                                               const int* __restrict__ labels,
                                               float* __restrict__ g_acc,
                                               unsigned int* __restrict__ g_cnt,
                                               float* __restrict__ out) {
    __shared__ float srow[NN];
    __shared__ float posf[NN];
    __shared__ int   poslist[NN];
    __shared__ int   npos_cnt;
    __shared__ float wave_part[4];

    const int i = blockIdx.x;
    const int t = threadIdx.x;
    if (t == 0) npos_cnt = 0;
    __syncthreads();

    const int li = labels[i];
    for (int k = t; k < NN; k += 256) {
        srow[k] = S[i * NN + k];
        bool p  = (labels[k] == li) && (k != i);
        posf[k] = p ? 1.f : 0.f;
        if (p) {
            int idx = atomicAdd(&npos_cnt, 1);
            poslist[idx] = k;
        }
    }
    __syncthreads();

    const int cnt  = npos_cnt;             // positives excluding self
    const int wave = t >> 6, lane = t & 63;
    // sigmoid(clip(x/T,-50,50)) = 1/(1+exp2(clip(-x*100*log2e, +-50*log2e)))
    const float C1   = 100.0f * 1.44269504088896340736f;
    const float CLIP = 50.0f * 1.44269504088896340736f;

    float acc = 0.f;
    if (cnt > 0) {
        for (int idx = wave; idx <= cnt; idx += 4) {  // idx==cnt -> eye term j==i
            const int   j   = (idx == cnt) ? i : poslist[idx];
            const float sij = srow[j];
            float sum_all = 0.f, sum_pos = 0.f;
#pragma unroll
            for (int kk = 0; kk < 8; kk++) {
                const int k = lane + (kk << 6);
                float y = (sij - srow[k]) * C1;
                y = fminf(fmaxf(y, -CLIP), CLIP);
                float tt = 1.0f / (1.0f + exp2f(y));
                if (k == j) tt = 0.f;                 // (1-eye)[j,k]
                sum_all += tt;
                sum_pos += tt * posf[k];              // posf[i]==0 excludes k==i
            }
#pragma unroll
            for (int off = 32; off; off >>= 1) {
                sum_all += __shfl_down(sum_all, off);
                sum_pos += __shfl_down(sum_pos, off);
            }
            if (lane == 0) {
                const float den = 1.0f + sum_all;
                const float num = (j == i) ? 1.0f : (1.0f + sum_pos);
                acc += num / den;
            }
        }
    }
    if (lane == 0) wave_part[wave] = acc;
    __syncthreads();
    if (t == 0) {
        float block_val = 0.f;
        if (cnt > 0) {
            float tot = wave_part[0] + wave_part[1] + wave_part[2] + wave_part[3];
            block_val = tot / (float)(cnt + 1);
        }
        atomicAdd(g_acc, block_val);
        __threadfence();
        unsigned int done = atomicAdd(g_cnt, 1u);
        if (done == NN - 1) {                  // last block finishes the reduce
            float total = atomicAdd(g_acc, 0.0f);   // atomic read at coherence point
            out[0] = 1.0f - total / (float)NN;
        }
    }
}

extern "C" void kernel_launch(void* const* d_in, const int* in_sizes, int n_in,
                              void* d_out, int out_size, void* d_ws, size_t ws_size,
                              hipStream_t stream) {
    const float* preds  = (const float*)d_in[0];
    const int*   labels = (const int*)d_in[1];
    float* out = (float*)d_out;

    float*        S     = (float*)d_ws;                 // 512*512 floats = 1 MB
    float*        g_acc = (float*)d_ws + NN * NN;       // 1 float
    unsigned int* g_cnt = (unsigned int*)((float*)d_ws + NN * NN + 1);

    dim3 ggrid(NN / 32, NN / 32);
    sap_gemm<<<ggrid, 256, 0, stream>>>(preds, S, g_acc, g_cnt);
    sap_rows<<<NN, 256, 0, stream>>>(S, labels, g_acc, g_cnt, out);
}